// Round 1
// baseline (230.947 us; speedup 1.0000x reference)
//
#include <hip/hip_runtime.h>
#include <math.h>

typedef unsigned short u16;
typedef short short8 __attribute__((ext_vector_type(8)));
typedef float f32x4 __attribute__((ext_vector_type(4)));
typedef float f4 __attribute__((ext_vector_type(4)));
typedef unsigned short u16x4 __attribute__((ext_vector_type(4)));

// ---------- helpers ----------
__device__ __forceinline__ u16 f2bf(float f) {
  unsigned u = __builtin_bit_cast(unsigned, f);
  u += 0x7fffu + ((u >> 16) & 1u);
  return (u16)(u >> 16);
}

__device__ __forceinline__ void gload16(const void* g, void* l) {
  __builtin_amdgcn_global_load_lds((const __attribute__((address_space(1))) void*)g,
                                   (__attribute__((address_space(3))) void*)l, 16, 0, 0);
}

// ---------- fp32 -> bf16 cast (x) ----------
__global__ __launch_bounds__(256) void convert_x_kernel(const float* __restrict__ in,
                                                        u16* __restrict__ out, int n4) {
  int i = blockIdx.x * 256 + threadIdx.x;
  int stride = gridDim.x * 256;
  for (; i < n4; i += stride) {
    f4 v = ((const f4*)in)[i];
    u16x4 o;
    o[0] = f2bf(v[0]); o[1] = f2bf(v[1]); o[2] = f2bf(v[2]); o[3] = f2bf(v[3]);
    ((u16x4*)out)[i] = o;
  }
}

// ---------- fp32 [R][C] -> bf16 [C][R] transpose ----------
__global__ __launch_bounds__(256) void transpose_w_kernel(const float* __restrict__ in,
                                                          u16* __restrict__ out, int R, int C) {
  __shared__ float t[32][33];
  int j0 = blockIdx.x * 32, i0 = blockIdx.y * 32;
  int tx = threadIdx.x, ty = threadIdx.y;  // 32 x 8
#pragma unroll
  for (int k = 0; k < 4; ++k) t[ty + 8 * k][tx] = in[(size_t)(i0 + ty + 8 * k) * C + j0 + tx];
  __syncthreads();
#pragma unroll
  for (int k = 0; k < 4; ++k)
    out[(size_t)(j0 + ty + 8 * k) * R + i0 + tx] = f2bf(t[tx][ty + 8 * k]);
}

// ---------- V transpose: qkv v-part [t][d] -> Vt[bh][d][t] (bf16) ----------
__global__ __launch_bounds__(256) void transV_kernel(const u16* __restrict__ qkv,
                                                     u16* __restrict__ Vt) {
  __shared__ u16 t[32][72];
  int t0 = blockIdx.x * 32;
  int bh = blockIdx.y, b = bh >> 4, h = bh & 15;
  int tid = threadIdx.x;
  int tx = tid & 63, ty = tid >> 6;  // 64 x 4
#pragma unroll
  for (int p = 0; p < 8; ++p) {
    int tt = ty + p * 4;
    t[tt][tx] = qkv[(size_t)(b * 2048 + t0 + tt) * 3072 + 2048 + h * 64 + tx];
  }
  __syncthreads();
  int t2 = tid & 31, d2 = tid >> 5;  // 32 t x 8 d
#pragma unroll
  for (int p = 0; p < 8; ++p) {
    int d = d2 + p * 8;
    Vt[(size_t)bh * 131072 + (size_t)d * 2048 + t0 + t2] = t[t2][d];
  }
}

// ---------- GEMM: C[m][n] = sum_k A[m][k] * Bt[n][k], bf16 in, fp32 acc ----------
// BM=BN=128, BK=64, 256 threads (2x2 waves, 64x64 per wave)
template <int BF16_OUT>
__global__ __launch_bounds__(256) void gemm_kernel(const u16* __restrict__ A,
                                                   const u16* __restrict__ Bt,
                                                   void* __restrict__ Cv, int N, int K) {
  __shared__ __align__(16) u16 lA[128 * 64];
  __shared__ __align__(16) u16 lB[128 * 64];
  const int tid = threadIdx.x;
  const int w = tid >> 6, lane = tid & 63, lo = lane & 15, hi = lane >> 4;
  const int wm = w >> 1, wn = w & 1;
  const int m0 = blockIdx.y * 128, n0 = blockIdx.x * 128;
  f32x4 acc[4][4] = {};
  const int nkt = K >> 6;
  for (int kt = 0; kt < nkt; ++kt) {
    const int k0 = kt * 64;
    // stage 16KB A + 16KB B; source pre-swizzled so linear LDS dest + swizzled read agree
#pragma unroll
    for (int c = 0; c < 4; ++c) {
      int flat = tid + c * 256;
      int r = flat >> 3, kc = flat & 7;
      int kcs = kc ^ (r & 7);
      gload16(A + (size_t)(m0 + r) * K + k0 + kcs * 8, (char*)lA + flat * 16);
      gload16(Bt + (size_t)(n0 + r) * K + k0 + kcs * 8, (char*)lB + flat * 16);
    }
    __syncthreads();
#pragma unroll
    for (int kk = 0; kk < 2; ++kk) {
      short8 af[4], bf[4];
#pragma unroll
      for (int mf = 0; mf < 4; ++mf) {
        int row = wm * 64 + mf * 16 + lo;
        int addr = (row * 128 + kk * 64 + hi * 16) ^ ((row & 7) << 4);
        af[mf] = *(const short8*)((const char*)lA + addr);
      }
#pragma unroll
      for (int nf = 0; nf < 4; ++nf) {
        int row = wn * 64 + nf * 16 + lo;
        int addr = (row * 128 + kk * 64 + hi * 16) ^ ((row & 7) << 4);
        bf[nf] = *(const short8*)((const char*)lB + addr);
      }
#pragma unroll
      for (int mf = 0; mf < 4; ++mf)
#pragma unroll
        for (int nf = 0; nf < 4; ++nf)
          acc[mf][nf] = __builtin_amdgcn_mfma_f32_16x16x32_bf16(af[mf], bf[nf], acc[mf][nf], 0, 0, 0);
    }
    __syncthreads();
  }
#pragma unroll
  for (int mf = 0; mf < 4; ++mf)
#pragma unroll
    for (int nf = 0; nf < 4; ++nf)
#pragma unroll
      for (int r = 0; r < 4; ++r) {
        int row = m0 + wm * 64 + mf * 16 + hi * 4 + r;
        int col = n0 + wn * 64 + nf * 16 + lo;
        float v = acc[mf][nf][r];
        if (BF16_OUT)
          ((u16*)Cv)[(size_t)row * N + col] = f2bf(v);
        else
          ((float*)Cv)[(size_t)row * N + col] = v;
      }
}

// ---------- flash attention ----------
// grid (16 qtiles, 32 bh), 256 thr = 4 independent waves; wave owns 32 q rows.
__global__ __launch_bounds__(256) void attn_kernel(const u16* __restrict__ qkv,
                                                   const u16* __restrict__ Vt,
                                                   u16* __restrict__ yb) {
  __shared__ __align__(16) u16 pl[4][32][72];  // wave-private P tiles, stride 144B (9x16)
  const int tid = threadIdx.x, w = tid >> 6, lane = tid & 63, lo = lane & 15, hi = lane >> 4;
  const int qt = blockIdx.x, bh = blockIdx.y, b = bh >> 4, h = bh & 15;
  const int q0 = qt * 128 + w * 32;
  const float CS = 0.03125f * 1.44269504088896f;  // rsqrt(1024) * log2(e)

  short8 qf[2][2];
#pragma unroll
  for (int mf = 0; mf < 2; ++mf)
#pragma unroll
    for (int kk = 0; kk < 2; ++kk)
      qf[mf][kk] = *(const short8*)(qkv + (size_t)(b * 2048 + q0 + mf * 16 + lo) * 3072 +
                                    h * 64 + kk * 32 + hi * 8);

  float mrun[2][4], lrun[2][4];
  f32x4 yacc[2][4] = {};
#pragma unroll
  for (int mf = 0; mf < 2; ++mf)
#pragma unroll
    for (int r = 0; r < 4; ++r) { mrun[mf][r] = -INFINITY; lrun[mf][r] = 0.f; }

  const int nt = (q0 + 31) / 64 + 1;
  for (int it = 0; it < nt; ++it) {
    const int t0 = it * 64;
    // K fragments direct from global (L2-resident)
    short8 kf[4][2];
#pragma unroll
    for (int nf = 0; nf < 4; ++nf)
#pragma unroll
      for (int kk = 0; kk < 2; ++kk)
        kf[nf][kk] = *(const short8*)(qkv + (size_t)(b * 2048 + t0 + nf * 16 + lo) * 3072 +
                                      1024 + h * 64 + kk * 32 + hi * 8);
    f32x4 s[2][4] = {};
#pragma unroll
    for (int kk = 0; kk < 2; ++kk)
#pragma unroll
      for (int mf = 0; mf < 2; ++mf)
#pragma unroll
        for (int nf = 0; nf < 4; ++nf)
          s[mf][nf] = __builtin_amdgcn_mfma_f32_16x16x32_bf16(qf[mf][kk], kf[nf][kk], s[mf][nf], 0, 0, 0);

    // scale + causal mask + tile row-max
    float pmax[2][4];
#pragma unroll
    for (int mf = 0; mf < 2; ++mf)
#pragma unroll
      for (int r = 0; r < 4; ++r) pmax[mf][r] = -INFINITY;
#pragma unroll
    for (int mf = 0; mf < 2; ++mf)
#pragma unroll
      for (int nf = 0; nf < 4; ++nf) {
        int kc = t0 + nf * 16 + lo;
#pragma unroll
        for (int r = 0; r < 4; ++r) {
          int qr = q0 + mf * 16 + hi * 4 + r;
          float v = s[mf][nf][r] * CS;
          v = (kc <= qr) ? v : -INFINITY;
          s[mf][nf][r] = v;
          pmax[mf][r] = fmaxf(pmax[mf][r], v);
        }
      }
#pragma unroll
    for (int mf = 0; mf < 2; ++mf)
#pragma unroll
      for (int r = 0; r < 4; ++r)
#pragma unroll
        for (int d = 1; d < 16; d <<= 1) pmax[mf][r] = fmaxf(pmax[mf][r], __shfl_xor(pmax[mf][r], d));

    float fac[2][4], nm[2][4], rsum[2][4];
#pragma unroll
    for (int mf = 0; mf < 2; ++mf)
#pragma unroll
      for (int r = 0; r < 4; ++r) {
        nm[mf][r] = fmaxf(mrun[mf][r], pmax[mf][r]);
        fac[mf][r] = exp2f(mrun[mf][r] - nm[mf][r]);
        rsum[mf][r] = 0.f;
      }
#pragma unroll
    for (int mf = 0; mf < 2; ++mf)
#pragma unroll
      for (int nf = 0; nf < 4; ++nf)
#pragma unroll
        for (int r = 0; r < 4; ++r) {
          float p = exp2f(s[mf][nf][r] - nm[mf][r]);
          s[mf][nf][r] = p;
          rsum[mf][r] += p;
        }
#pragma unroll
    for (int mf = 0; mf < 2; ++mf)
#pragma unroll
      for (int r = 0; r < 4; ++r) {
#pragma unroll
        for (int d = 1; d < 16; d <<= 1) rsum[mf][r] += __shfl_xor(rsum[mf][r], d);
        lrun[mf][r] = lrun[mf][r] * fac[mf][r] + rsum[mf][r];
        mrun[mf][r] = nm[mf][r];
      }
#pragma unroll
    for (int mf = 0; mf < 2; ++mf)
#pragma unroll
      for (int nf = 0; nf < 4; ++nf)
#pragma unroll
        for (int r = 0; r < 4; ++r) yacc[mf][nf][r] *= fac[mf][r];

    // P (D-layout) -> LDS, reload as A-fragments
#pragma unroll
    for (int mf = 0; mf < 2; ++mf)
#pragma unroll
      for (int nf = 0; nf < 4; ++nf)
#pragma unroll
        for (int r = 0; r < 4; ++r)
          pl[w][mf * 16 + hi * 4 + r][nf * 16 + lo] = f2bf(s[mf][nf][r]);

#pragma unroll
    for (int kk2 = 0; kk2 < 2; ++kk2) {
      short8 pa[2];
#pragma unroll
      for (int mf = 0; mf < 2; ++mf)
        pa[mf] = *(const short8*)&pl[w][mf * 16 + lo][kk2 * 32 + hi * 8];
      short8 vf[4];
#pragma unroll
      for (int nf = 0; nf < 4; ++nf)
        vf[nf] = *(const short8*)(Vt + (size_t)bh * 131072 + (size_t)(nf * 16 + lo) * 2048 +
                                  t0 + kk2 * 32 + hi * 8);
#pragma unroll
      for (int mf = 0; mf < 2; ++mf)
#pragma unroll
        for (int nf = 0; nf < 4; ++nf)
          yacc[mf][nf] = __builtin_amdgcn_mfma_f32_16x16x32_bf16(pa[mf], vf[nf], yacc[mf][nf], 0, 0, 0);
    }
  }

#pragma unroll
  for (int mf = 0; mf < 2; ++mf) {
    float inv[4];
#pragma unroll
    for (int r = 0; r < 4; ++r) inv[r] = 1.0f / lrun[mf][r];
#pragma unroll
    for (int nf = 0; nf < 4; ++nf)
#pragma unroll
      for (int r = 0; r < 4; ++r)
        yb[(size_t)(b * 2048 + q0 + mf * 16 + hi * 4 + r) * 1024 + h * 64 + nf * 16 + lo] =
            f2bf(yacc[mf][nf][r] * inv[r]);
  }
}

extern "C" void kernel_launch(void* const* d_in, const int* in_sizes, int n_in,
                              void* d_out, int out_size, void* d_ws, size_t ws_size,
                              hipStream_t stream) {
  const float* x = (const float*)d_in[0];    // [4096][1024]
  const float* Wa = (const float*)d_in[1];   // [1024][3072]
  const float* Wp = (const float*)d_in[2];   // [1024][1024]
  char* ws = (char*)d_ws;
  u16* xb   = (u16*)(ws);              // [4096][1024] bf16
  u16* Wat  = (u16*)(ws + 8388608);    // [3072][1024] bf16 (W_attn^T)
  u16* Wpt  = (u16*)(ws + 14680064);   // [1024][1024] bf16 (W_proj^T)
  u16* qkvb = (u16*)(ws + 16777216);   // [4096][3072] bf16
  u16* Vt   = (u16*)(ws + 41943040);   // [32][64][2048] bf16
  u16* yb   = (u16*)(ws + 50331648);   // [4096][1024] bf16

  convert_x_kernel<<<1024, 256, 0, stream>>>(x, xb, 4194304 / 4);
  transpose_w_kernel<<<dim3(96, 32), dim3(32, 8), 0, stream>>>(Wa, Wat, 1024, 3072);
  transpose_w_kernel<<<dim3(32, 32), dim3(32, 8), 0, stream>>>(Wp, Wpt, 1024, 1024);
  gemm_kernel<1><<<dim3(24, 32), 256, 0, stream>>>(xb, Wat, (void*)qkvb, 3072, 1024);
  transV_kernel<<<dim3(64, 32), 256, 0, stream>>>(qkvb, Vt);
  attn_kernel<<<dim3(16, 32), 256, 0, stream>>>(qkvb, Vt, yb);
  gemm_kernel<0><<<dim3(8, 32), 256, 0, stream>>>(yb, Wpt, d_out, 1024, 1024);
}

// Round 2
// 178.604 us; speedup vs baseline: 1.2931x; 1.2931x over previous
//
#include <hip/hip_runtime.h>
#include <math.h>

typedef unsigned short u16;
typedef short short8 __attribute__((ext_vector_type(8)));
typedef float f32x4 __attribute__((ext_vector_type(4)));
typedef float f4 __attribute__((ext_vector_type(4)));
typedef unsigned short u16x4 __attribute__((ext_vector_type(4)));

// ---------- helpers ----------
__device__ __forceinline__ u16 f2bf(float f) {
  unsigned u = __builtin_bit_cast(unsigned, f);
  u += 0x7fffu + ((u >> 16) & 1u);
  return (u16)(u >> 16);
}

__device__ __forceinline__ void gload16(const void* g, void* l) {
  __builtin_amdgcn_global_load_lds((const __attribute__((address_space(1))) void*)g,
                                   (__attribute__((address_space(3))) void*)l, 16, 0, 0);
}

// ---------- fp32 -> bf16 cast (x) ----------
__global__ __launch_bounds__(256) void convert_x_kernel(const float* __restrict__ in,
                                                        u16* __restrict__ out, int n4) {
  int i = blockIdx.x * 256 + threadIdx.x;
  int stride = gridDim.x * 256;
  for (; i < n4; i += stride) {
    f4 v = ((const f4*)in)[i];
    u16x4 o;
    o[0] = f2bf(v[0]); o[1] = f2bf(v[1]); o[2] = f2bf(v[2]); o[3] = f2bf(v[3]);
    ((u16x4*)out)[i] = o;
  }
}

// ---------- fp32 [R][C] -> bf16 [C][R] transpose ----------
__global__ __launch_bounds__(256) void transpose_w_kernel(const float* __restrict__ in,
                                                          u16* __restrict__ out, int R, int C) {
  __shared__ float t[32][33];
  int j0 = blockIdx.x * 32, i0 = blockIdx.y * 32;
  int tx = threadIdx.x, ty = threadIdx.y;  // 32 x 8
#pragma unroll
  for (int k = 0; k < 4; ++k) t[ty + 8 * k][tx] = in[(size_t)(i0 + ty + 8 * k) * C + j0 + tx];
  __syncthreads();
#pragma unroll
  for (int k = 0; k < 4; ++k)
    out[(size_t)(j0 + ty + 8 * k) * R + i0 + tx] = f2bf(t[tx][ty + 8 * k]);
}

// ---------- V transpose: qkv v-part [t][d] -> Vt[bh][d][t] (bf16) ----------
__global__ __launch_bounds__(256) void transV_kernel(const u16* __restrict__ qkv,
                                                     u16* __restrict__ Vt) {
  __shared__ u16 t[32][72];
  int t0 = blockIdx.x * 32;
  int bh = blockIdx.y, b = bh >> 4, h = bh & 15;
  int tid = threadIdx.x;
  int tx = tid & 63, ty = tid >> 6;  // 64 x 4
#pragma unroll
  for (int p = 0; p < 8; ++p) {
    int tt = ty + p * 4;
    t[tt][tx] = qkv[(size_t)(b * 2048 + t0 + tt) * 3072 + 2048 + h * 64 + tx];
  }
  __syncthreads();
  int t2 = tid & 31, d2 = tid >> 5;  // 32 t x 8 d
#pragma unroll
  for (int p = 0; p < 8; ++p) {
    int d = d2 + p * 8;
    Vt[(size_t)bh * 131072 + (size_t)d * 2048 + t0 + t2] = t[t2][d];
  }
}

// ---------- GEMM: C[m][n] = sum_k A[m][k] * Bt[n][k], bf16 in, fp32 acc ----------
// BM=BN=128, BK=64, 256 threads (2x2 waves, 64x64 per wave)
template <int BF16_OUT>
__global__ __launch_bounds__(256) void gemm_kernel(const u16* __restrict__ A,
                                                   const u16* __restrict__ Bt,
                                                   void* __restrict__ Cv, int N, int K) {
  __shared__ __align__(16) u16 lA[128 * 64];
  __shared__ __align__(16) u16 lB[128 * 64];
  const int tid = threadIdx.x;
  const int w = tid >> 6, lane = tid & 63, lo = lane & 15, hi = lane >> 4;
  const int wm = w >> 1, wn = w & 1;
  const int m0 = blockIdx.y * 128, n0 = blockIdx.x * 128;
  f32x4 acc[4][4] = {};
  const int nkt = K >> 6;
  for (int kt = 0; kt < nkt; ++kt) {
    const int k0 = kt * 64;
#pragma unroll
    for (int c = 0; c < 4; ++c) {
      int flat = tid + c * 256;
      int r = flat >> 3, kc = flat & 7;
      int kcs = kc ^ (r & 7);
      gload16(A + (size_t)(m0 + r) * K + k0 + kcs * 8, (char*)lA + flat * 16);
      gload16(Bt + (size_t)(n0 + r) * K + k0 + kcs * 8, (char*)lB + flat * 16);
    }
    __syncthreads();
#pragma unroll
    for (int kk = 0; kk < 2; ++kk) {
      short8 af[4], bf[4];
#pragma unroll
      for (int mf = 0; mf < 4; ++mf) {
        int row = wm * 64 + mf * 16 + lo;
        int addr = (row * 128 + kk * 64 + hi * 16) ^ ((row & 7) << 4);
        af[mf] = *(const short8*)((const char*)lA + addr);
      }
#pragma unroll
      for (int nf = 0; nf < 4; ++nf) {
        int row = wn * 64 + nf * 16 + lo;
        int addr = (row * 128 + kk * 64 + hi * 16) ^ ((row & 7) << 4);
        bf[nf] = *(const short8*)((const char*)lB + addr);
      }
#pragma unroll
      for (int mf = 0; mf < 4; ++mf)
#pragma unroll
        for (int nf = 0; nf < 4; ++nf)
          acc[mf][nf] = __builtin_amdgcn_mfma_f32_16x16x32_bf16(af[mf], bf[nf], acc[mf][nf], 0, 0, 0);
    }
    __syncthreads();
  }
#pragma unroll
  for (int mf = 0; mf < 4; ++mf)
#pragma unroll
    for (int nf = 0; nf < 4; ++nf)
#pragma unroll
      for (int r = 0; r < 4; ++r) {
        int row = m0 + wm * 64 + mf * 16 + hi * 4 + r;
        int col = n0 + wn * 64 + nf * 16 + lo;
        float v = acc[mf][nf][r];
        if (BF16_OUT)
          ((u16*)Cv)[(size_t)row * N + col] = f2bf(v);
        else
          ((float*)Cv)[(size_t)row * N + col] = v;
      }
}

// ---------- flash attention ----------
// 2048 single-wave blocks (64 thr). Block bx: q-tile qt = 63 - bx/32 (big first,
// dynamic load balance), bh = bx & 31. Wave owns 32 q rows, KV tiles of 64.
// Swapped QK^T: st = mfma(K,Q) puts q on lane&15 -> row stats are lane-local
// (15 VALU max/sum + 2 shfl) instead of 4-deep shuffle chains.
__global__ __launch_bounds__(64, 3) void attn_kernel(const u16* __restrict__ qkv,
                                                     const u16* __restrict__ Vt,
                                                     u16* __restrict__ yb) {
  __shared__ __align__(16) u16 pl[32][72];     // P tile [q][k], stride 144B
  __shared__ __align__(16) float rowstat[32];  // per-q fac / inv broadcast
  const int lane = threadIdx.x;
  const int lo = lane & 15, hi = lane >> 4;
  const int bx = blockIdx.x;
  const int qt = 63 - (bx >> 5);
  const int bh = bx & 31, b = bh >> 4, h = bh & 15;
  const int q0 = qt * 32;
  const float CS = 0.03125f * 1.44269504088896f;  // rsqrt(1024) * log2(e)

  short8 qf[2][2];
#pragma unroll
  for (int m = 0; m < 2; ++m)
#pragma unroll
    for (int kk = 0; kk < 2; ++kk)
      qf[m][kk] = *(const short8*)(qkv + (size_t)(b * 2048 + q0 + m * 16 + lo) * 3072 +
                                   h * 64 + kk * 32 + hi * 8);

  float mrun[2] = {-INFINITY, -INFINITY}, lrun[2] = {0.f, 0.f};
  f32x4 yacc[2][4] = {};

  const int nt = q0 / 64 + 1;
  for (int it = 0; it < nt; ++it) {
    const int t0 = it * 64;
    short8 kf[4][2];
#pragma unroll
    for (int n = 0; n < 4; ++n)
#pragma unroll
      for (int kk = 0; kk < 2; ++kk)
        kf[n][kk] = *(const short8*)(qkv + (size_t)(b * 2048 + t0 + n * 16 + lo) * 3072 +
                                     1024 + h * 64 + kk * 32 + hi * 8);
    f32x4 st[4][2] = {};  // st[n][m][r] = S^T[k = t0+n*16+4hi+r][q = q0+m*16+lo]
#pragma unroll
    for (int kk = 0; kk < 2; ++kk)
#pragma unroll
      for (int n = 0; n < 4; ++n)
#pragma unroll
        for (int m = 0; m < 2; ++m)
          st[n][m] = __builtin_amdgcn_mfma_f32_16x16x32_bf16(kf[n][kk], qf[m][kk], st[n][m], 0, 0, 0);

    float mx[2] = {-INFINITY, -INFINITY};
    if (t0 + 63 > q0) {  // wave-uniform: tile needs causal mask
#pragma unroll
      for (int m = 0; m < 2; ++m) {
        const int q = q0 + m * 16 + lo;
#pragma unroll
        for (int n = 0; n < 4; ++n)
#pragma unroll
          for (int r = 0; r < 4; ++r) {
            const int k = t0 + n * 16 + hi * 4 + r;
            float v = st[n][m][r] * CS;
            v = (k <= q) ? v : -INFINITY;
            st[n][m][r] = v;
            mx[m] = fmaxf(mx[m], v);
          }
      }
    } else {
#pragma unroll
      for (int m = 0; m < 2; ++m)
#pragma unroll
        for (int n = 0; n < 4; ++n)
#pragma unroll
          for (int r = 0; r < 4; ++r) {
            float v = st[n][m][r] * CS;
            st[n][m][r] = v;
            mx[m] = fmaxf(mx[m], v);
          }
    }
    float fac[2];
#pragma unroll
    for (int m = 0; m < 2; ++m) {
      mx[m] = fmaxf(mx[m], __shfl_xor(mx[m], 16));
      mx[m] = fmaxf(mx[m], __shfl_xor(mx[m], 32));
      float nm = fmaxf(mrun[m], mx[m]);
      fac[m] = exp2f(mrun[m] - nm);
      mrun[m] = nm;
    }
    float rs[2] = {0.f, 0.f};
#pragma unroll
    for (int m = 0; m < 2; ++m)
#pragma unroll
      for (int n = 0; n < 4; ++n)
#pragma unroll
        for (int r = 0; r < 4; ++r) {
          float p = exp2f(st[n][m][r] - mrun[m]);
          st[n][m][r] = p;
          rs[m] += p;
        }
#pragma unroll
    for (int m = 0; m < 2; ++m) {
      rs[m] += __shfl_xor(rs[m], 16);
      rs[m] += __shfl_xor(rs[m], 32);
      lrun[m] = lrun[m] * fac[m] + rs[m];
    }
    if (hi == 0) { rowstat[lo] = fac[0]; rowstat[16 + lo] = fac[1]; }
    // pack P^T lane-regs -> pl[q][k] : r=0..3 contiguous in k -> 8B stores
#pragma unroll
    for (int m = 0; m < 2; ++m)
#pragma unroll
      for (int n = 0; n < 4; ++n) {
        u16x4 pk;
#pragma unroll
        for (int r = 0; r < 4; ++r) pk[r] = f2bf(st[n][m][r]);
        *(u16x4*)&pl[m * 16 + lo][n * 16 + hi * 4] = pk;
      }
    __syncthreads();
    // rescale yacc (fac for q = mf*16+4hi+r via LDS broadcast)
#pragma unroll
    for (int mf = 0; mf < 2; ++mf) {
      f32x4 fv = *(const f32x4*)&rowstat[mf * 16 + hi * 4];
#pragma unroll
      for (int nf = 0; nf < 4; ++nf)
#pragma unroll
        for (int r = 0; r < 4; ++r) yacc[mf][nf][r] *= fv[r];
    }
    // PV
#pragma unroll
    for (int kk2 = 0; kk2 < 2; ++kk2) {
      short8 pa[2], vf[4];
#pragma unroll
      for (int mf = 0; mf < 2; ++mf)
        pa[mf] = *(const short8*)&pl[mf * 16 + lo][kk2 * 32 + hi * 8];
#pragma unroll
      for (int nf = 0; nf < 4; ++nf)
        vf[nf] = *(const short8*)(Vt + (size_t)bh * 131072 + (size_t)(nf * 16 + lo) * 2048 +
                                  t0 + kk2 * 32 + hi * 8);
#pragma unroll
      for (int mf = 0; mf < 2; ++mf)
#pragma unroll
        for (int nf = 0; nf < 4; ++nf)
          yacc[mf][nf] = __builtin_amdgcn_mfma_f32_16x16x32_bf16(pa[mf], vf[nf], yacc[mf][nf], 0, 0, 0);
    }
    __syncthreads();  // protect pl/rowstat reads from next-iter writes
  }
  // epilogue: inv(lrun) broadcast via rowstat
  if (hi == 0) { rowstat[lo] = 1.f / lrun[0]; rowstat[16 + lo] = 1.f / lrun[1]; }
  __syncthreads();
#pragma unroll
  for (int mf = 0; mf < 2; ++mf) {
    f32x4 iv = *(const f32x4*)&rowstat[mf * 16 + hi * 4];
#pragma unroll
    for (int nf = 0; nf < 4; ++nf)
#pragma unroll
      for (int r = 0; r < 4; ++r)
        yb[(size_t)(b * 2048 + q0 + mf * 16 + hi * 4 + r) * 1024 + h * 64 + nf * 16 + lo] =
            f2bf(yacc[mf][nf][r] * iv[r]);
  }
}

extern "C" void kernel_launch(void* const* d_in, const int* in_sizes, int n_in,
                              void* d_out, int out_size, void* d_ws, size_t ws_size,
                              hipStream_t stream) {
  const float* x = (const float*)d_in[0];    // [4096][1024]
  const float* Wa = (const float*)d_in[1];   // [1024][3072]
  const float* Wp = (const float*)d_in[2];   // [1024][1024]
  char* ws = (char*)d_ws;
  u16* xb   = (u16*)(ws);              // [4096][1024] bf16
  u16* Wat  = (u16*)(ws + 8388608);    // [3072][1024] bf16 (W_attn^T)
  u16* Wpt  = (u16*)(ws + 14680064);   // [1024][1024] bf16 (W_proj^T)
  u16* qkvb = (u16*)(ws + 16777216);   // [4096][3072] bf16
  u16* Vt   = (u16*)(ws + 41943040);   // [32][64][2048] bf16
  u16* yb   = (u16*)(ws + 50331648);   // [4096][1024] bf16

  convert_x_kernel<<<1024, 256, 0, stream>>>(x, xb, 4194304 / 4);
  transpose_w_kernel<<<dim3(96, 32), dim3(32, 8), 0, stream>>>(Wa, Wat, 1024, 3072);
  transpose_w_kernel<<<dim3(32, 32), dim3(32, 8), 0, stream>>>(Wp, Wpt, 1024, 1024);
  gemm_kernel<1><<<dim3(24, 32), 256, 0, stream>>>(xb, Wat, (void*)qkvb, 3072, 1024);
  transV_kernel<<<dim3(64, 32), 256, 0, stream>>>(qkvb, Vt);
  attn_kernel<<<2048, 64, 0, stream>>>(qkvb, Vt, yb);
  gemm_kernel<0><<<dim3(8, 32), 256, 0, stream>>>(yb, Wpt, d_out, 1024, 1024);
}